// Round 16
// baseline (360.332 us; speedup 1.0000x reference)
//
#include <hip/hip_runtime.h>
#include <math.h>

#define NN 20000
#define EE 320000
#define ETOT 340000   // EE + NN self-loops
#define NHEADS 8
#define HID 64
#define HCV 512       // NHEADS*HID
#define IND 128
#define OUTD 128
#define NEG_SLOPE 0.2f

typedef __attribute__((ext_vector_type(8))) _Float16 half8;
typedef __attribute__((ext_vector_type(2))) _Float16 half2v;
typedef __attribute__((ext_vector_type(4))) float floatx4;

// ---------------- prep: W cvt + x cvt + w1 projection + zero cnt ----------------
__device__ __forceinline__ void cvt_one(const float* W, _Float16* T, int idx, int K, int N) {
    int k = idx / N, n = idx - k * N;
    T[(size_t)n * K + k] = (_Float16)W[idx];
}

#define S1 (IND * HCV)
#define S2 (HCV * HCV)
#define S3 (HCV * OUTD)
#define STOT (S1 + S2 + S3)
#define XTOT (NN * IND)
__global__ void prep_kernel(const float* __restrict__ W1, const float* __restrict__ W2,
                            const float* __restrict__ W3, const float* __restrict__ x,
                            const float* __restrict__ as1, const float* __restrict__ ad1,
                            _Float16* __restrict__ T1, _Float16* __restrict__ T2,
                            _Float16* __restrict__ T3, _Float16* __restrict__ xh,
                            float* __restrict__ w1p, int* __restrict__ cnt) {
    int idx = blockIdx.x * blockDim.x + threadIdx.x;
    if (idx < S1) cvt_one(W1, T1, idx, IND, HCV);
    else if (idx < S1 + S2) cvt_one(W2, T2, idx - S1, HCV, HCV);
    else if (idx < STOT) cvt_one(W3, T3, idx - S1 - S2, HCV, OUTD);
    else if (idx < STOT + NN) cnt[idx - STOT] = 0;
    else if (idx < STOT + NN + XTOT) {
        int j = idx - STOT - NN;
        xh[j] = (_Float16)x[j];
    } else if (idx < STOT + NN + XTOT + IND * 16) {
        int j = idx - STOT - NN - XTOT;
        int c = j >> 4, o = j & 15;
        int hh = o & 7;
        const float* av = (o < 8) ? as1 : ad1;
        float s = 0.f;
        #pragma unroll 8
        for (int jj = 0; jj < HID; jj++)
            s = fmaf(W1[c * HCV + hh * HID + jj], av[hh * HID + jj], s);
        w1p[c * 16 + o] = s;
    }
}

// ---------------- CSR build ----------------

__global__ void count_kernel(const int* __restrict__ ei, int* __restrict__ cnt) {
    int i = blockIdx.x * blockDim.x + threadIdx.x;
    if (i >= ETOT) return;
    int v = (i < EE) ? ei[EE + i] : (i - EE);
    atomicAdd(&cnt[v], 1);
}

#define SCH 20
__global__ __launch_bounds__(1024) void scan_kernel(const int* __restrict__ cnt,
                                                    int* __restrict__ row_ptr,
                                                    int* __restrict__ cursor) {
    __shared__ int wtot[16];
    __shared__ int woff[16];
    int t = threadIdx.x;
    int lane = t & 63;
    int wid = t >> 6;
    int base = t * SCH;
    int vals[SCH];
    int s = 0;
    #pragma unroll
    for (int i = 0; i < SCH; i++) {
        int idx = base + i;
        int v = (idx < NN) ? cnt[idx] : 0;
        vals[i] = v;
        s += v;
    }
    int incl = s;
    #pragma unroll
    for (int off = 1; off < 64; off <<= 1) {
        int u = __shfl_up(incl, off);
        if (lane >= off) incl += u;
    }
    int excl = incl - s;
    if (lane == 63) wtot[wid] = incl;
    __syncthreads();
    if (t == 0) {
        int run = 0;
        #pragma unroll
        for (int j = 0; j < 16; j++) { woff[j] = run; run += wtot[j]; }
        row_ptr[NN] = run;
    }
    __syncthreads();
    int run = woff[wid] + excl;
    #pragma unroll
    for (int i = 0; i < SCH; i++) {
        int idx = base + i;
        if (idx < NN) { row_ptr[idx] = run; cursor[idx] = run; run += vals[i]; }
    }
}

__global__ void fill_kernel(const int* __restrict__ ei, int* __restrict__ cursor,
                            int* __restrict__ csr_src) {
    int i = blockIdx.x * blockDim.x + threadIdx.x;
    if (i >= ETOT) return;
    int u, v;
    if (i < EE) { u = ei[i]; v = ei[EE + i]; }
    else        { u = i - EE; v = i - EE; }
    int pos = atomicAdd(&cursor[v], 1);
    csr_src[pos] = u;
}

// ---------------- layer-1 half-logits from x (thin dot) ----------------
__global__ void al1_thin(const float* __restrict__ x, const float* __restrict__ w1p,
                         float* __restrict__ als, float* __restrict__ ald) {
    int gid = blockIdx.x * blockDim.x + threadIdx.x;
    int node = gid >> 4, o = gid & 15;
    if (node >= NN) return;
    const float* xr = x + (size_t)node * IND;
    float s = 0.f;
    #pragma unroll 4
    for (int c = 0; c < IND; c++)
        s = fmaf(xr[c], w1p[c * 16 + o], s);
    if (o < 8) als[node * 8 + o] = s;
    else       ald[node * 8 + (o - 8)] = s;
}

// ---------------- layer-1 gather: wave per node, per-head agg of x, unroll 4 ----------------
__global__ __launch_bounds__(256) void gather1_kernel(const _Float16* __restrict__ xh,
                                                      const int* __restrict__ row_ptr,
                                                      const int* __restrict__ csr_src,
                                                      const float* __restrict__ als,
                                                      const float* __restrict__ ald,
                                                      _Float16* __restrict__ xagg) {
    int lane = threadIdx.x & 63;
    int v = blockIdx.x * 4 + (threadIdx.x >> 6);
    if (v >= NN) return;
    int hd = lane >> 3;
    int cg = lane & 7;
    float adst = ald[v * NHEADS + hd];
    int s0 = row_ptr[v], s1 = row_ptr[v + 1];
    float acc[16] = {};
    float l = 0.f;
    int i = s0;
    for (; i + 4 <= s1; i += 4) {
        int u[4]; float p[4];
        #pragma unroll
        for (int e = 0; e < 4; e++) u[e] = csr_src[i + e];
        #pragma unroll
        for (int e = 0; e < 4; e++) {
            float t = als[u[e] * NHEADS + hd] + adst;
            t = (t > 0.f) ? t : NEG_SLOPE * t;
            p[e] = __expf(fminf(t, 80.f));
        }
        half8 a[4], b[4];
        #pragma unroll
        for (int e = 0; e < 4; e++) {
            a[e] = *(const half8*)&xh[(size_t)u[e] * IND + cg * 16];
            b[e] = *(const half8*)&xh[(size_t)u[e] * IND + cg * 16 + 8];
        }
        #pragma unroll
        for (int e = 0; e < 4; e++) {
            l += p[e];
            #pragma unroll
            for (int j = 0; j < 8; j++) {
                acc[j]     = fmaf(p[e], (float)a[e][j], acc[j]);
                acc[j + 8] = fmaf(p[e], (float)b[e][j], acc[j + 8]);
            }
        }
    }
    for (; i < s1; i++) {
        int u0 = csr_src[i];
        float t0 = als[u0 * NHEADS + hd] + adst;
        t0 = (t0 > 0.f) ? t0 : NEG_SLOPE * t0;
        float p0 = __expf(fminf(t0, 80.f));
        half8 a0 = *(const half8*)&xh[(size_t)u0 * IND + cg * 16];
        half8 b0 = *(const half8*)&xh[(size_t)u0 * IND + cg * 16 + 8];
        l += p0;
        #pragma unroll
        for (int j = 0; j < 8; j++) {
            acc[j]     = fmaf(p0, (float)a0[j], acc[j]);
            acc[j + 8] = fmaf(p0, (float)b0[j], acc[j + 8]);
        }
    }
    float inv = 1.f / (l + 1e-16f);
    half8 o0, o1;
    #pragma unroll
    for (int j = 0; j < 8; j++) {
        o0[j] = (_Float16)(acc[j] * inv);
        o1[j] = (_Float16)(acc[j + 8] * inv);
    }
    size_t base = (size_t)v * (NHEADS * IND) + hd * IND + cg * 16;
    *(half8*)&xagg[base] = o0;
    *(half8*)&xagg[base + 8] = o1;
}

// ---------------- block-diagonal GEMM (layer 1) ----------------
#define LDK 40
__global__ __launch_bounds__(256) void gemm1_bd(const _Float16* __restrict__ xagg,
                                                const _Float16* __restrict__ Bt,
                                                const float* __restrict__ bias,
                                                _Float16* __restrict__ gact,
                                                int M) {
    __shared__ _Float16 sA[64 * LDK];
    __shared__ _Float16 sB[64 * LDK];
    int tid = threadIdx.x;
    int lane = tid & 63;
    int wv = tid >> 6;
    int m0 = blockIdx.x * 64;
    int h = blockIdx.y;
    int quad = lane >> 4;
    int l15 = lane & 15;
    int arow = tid >> 2;
    int ac4 = tid & 3;

    floatx4 acc[4] = {};

    for (int k0 = 0; k0 < IND; k0 += 32) {
        {
            int gm = m0 + arow;
            int4 va;
            if (gm < M) va = *(const int4*)&xagg[(size_t)gm * (NHEADS * IND) + h * IND + k0 + ac4 * 8];
            else        va = make_int4(0, 0, 0, 0);
            *(int4*)&sA[arow * LDK + ac4 * 8] = va;
            int gn = h * 64 + arow;
            int4 vb = *(const int4*)&Bt[(size_t)gn * IND + k0 + ac4 * 8];
            *(int4*)&sB[arow * LDK + ac4 * 8] = vb;
        }
        __syncthreads();
        half8 a[4], b;
        #pragma unroll
        for (int i = 0; i < 4; i++)
            a[i] = *(const half8*)&sA[(i * 16 + l15) * LDK + quad * 8];
        b = *(const half8*)&sB[(wv * 16 + l15) * LDK + quad * 8];
        #pragma unroll
        for (int i = 0; i < 4; i++)
            acc[i] = __builtin_amdgcn_mfma_f32_16x16x32_f16(a[i], b, acc[i], 0, 0, 0);
        __syncthreads();
    }
    #pragma unroll
    for (int i = 0; i < 4; i++) {
        #pragma unroll
        for (int r = 0; r < 4; r++) {
            int gm = m0 + i * 16 + quad * 4 + r;
            if (gm < M) {
                int col = h * 64 + wv * 16 + l15;
                float o = acc[i][r] + bias[col];
                o = (o > 0.f) ? o : (__expf(o) - 1.f);
                gact[(size_t)gm * HCV + col] = (_Float16)o;
            }
        }
    }
}

// ---------------- MFMA GEMM 64x128 (layer 2): f16, fused al epilogue ----------------
__global__ __launch_bounds__(256) void gemm_l2(const _Float16* __restrict__ A,
                                               const _Float16* __restrict__ Bt,
                                               _Float16* __restrict__ C16,
                                               const float* __restrict__ a_src,
                                               const float* __restrict__ a_dst,
                                               float* __restrict__ als,
                                               float* __restrict__ ald,
                                               int M, int K) {
    __shared__ _Float16 sA[64 * LDK];
    __shared__ _Float16 sB[128 * LDK];
    __shared__ float psum_s[4][64];
    __shared__ float psum_d[4][64];
    int tid = threadIdx.x;
    int lane = tid & 63;
    int wv = tid >> 6;
    int m0 = blockIdx.x * 64, n0 = blockIdx.y * 128;
    int quad = lane >> 4;
    int l15 = lane & 15;
    int arow = tid >> 2;
    int ac4 = tid & 3;

    floatx4 acc[4][2] = {};

    for (int k0 = 0; k0 < K; k0 += 32) {
        {
            int gm = m0 + arow;
            int4 va;
            if (gm < M) va = *(const int4*)&A[(size_t)gm * K + k0 + ac4 * 8];
            else        va = make_int4(0, 0, 0, 0);
            *(int4*)&sA[arow * LDK + ac4 * 8] = va;
            #pragma unroll
            for (int r = 0; r < 2; r++) {
                int gn = n0 + arow + r * 64;
                int4 vb = *(const int4*)&Bt[(size_t)gn * K + k0 + ac4 * 8];
                *(int4*)&sB[(arow + r * 64) * LDK + ac4 * 8] = vb;
            }
        }
        __syncthreads();
        half8 a[4], b[2];
        #pragma unroll
        for (int i = 0; i < 4; i++)
            a[i] = *(const half8*)&sA[(i * 16 + l15) * LDK + quad * 8];
        #pragma unroll
        for (int j = 0; j < 2; j++)
            b[j] = *(const half8*)&sB[(wv * 32 + j * 16 + l15) * LDK + quad * 8];
        #pragma unroll
        for (int i = 0; i < 4; i++)
            #pragma unroll
            for (int j = 0; j < 2; j++)
                acc[i][j] = __builtin_amdgcn_mfma_f32_16x16x32_f16(a[i], b[j], acc[i][j], 0, 0, 0);
        __syncthreads();
    }
    #pragma unroll
    for (int i = 0; i < 4; i++) {
        #pragma unroll
        for (int r = 0; r < 4; r++) {
            int gm = m0 + i * 16 + quad * 4 + r;
            if (gm < M) {
                #pragma unroll
                for (int j = 0; j < 2; j++)
                    C16[(size_t)gm * HCV + n0 + wv * 32 + j * 16 + l15] = (_Float16)acc[i][j][r];
            }
        }
    }
    int h0 = n0 >> 6;
    float as_v[2], ad_v[2];
    #pragma unroll
    for (int j = 0; j < 2; j++) {
        int dim = (wv * 32 + j * 16 + l15) & 63;
        int hh = h0 + (wv >> 1);
        as_v[j] = a_src[hh * HID + dim];
        ad_v[j] = a_dst[hh * HID + dim];
    }
    #pragma unroll
    for (int i = 0; i < 4; i++) {
        #pragma unroll
        for (int r = 0; r < 4; r++) {
            float ps = acc[i][0][r] * as_v[0] + acc[i][1][r] * as_v[1];
            float pd = acc[i][0][r] * ad_v[0] + acc[i][1][r] * ad_v[1];
            #pragma unroll
            for (int off = 1; off <= 8; off <<= 1) {
                ps += __shfl_xor(ps, off);
                pd += __shfl_xor(pd, off);
            }
            if (l15 == 0) {
                int row = i * 16 + quad * 4 + r;
                psum_s[wv][row] = ps;
                psum_d[wv][row] = pd;
            }
        }
    }
    __syncthreads();
    if (tid < 64) {
        int gm = m0 + tid;
        if (gm < M) {
            als[gm * NHEADS + h0]     = psum_s[0][tid] + psum_s[1][tid];
            als[gm * NHEADS + h0 + 1] = psum_s[2][tid] + psum_s[3][tid];
            ald[gm * NHEADS + h0]     = psum_d[0][tid] + psum_d[1][tid];
            ald[gm * NHEADS + h0 + 1] = psum_d[2][tid] + psum_d[3][tid];
        }
    }
}

// ---------------- MFMA GEMM 64x128 (layer 3): f16 C out, fused al3 ----------------
__global__ __launch_bounds__(256) void gemm3(const _Float16* __restrict__ A,
                                             const _Float16* __restrict__ Bt,
                                             _Float16* __restrict__ C16,
                                             const float* __restrict__ a_src,
                                             const float* __restrict__ a_dst,
                                             float* __restrict__ als,
                                             float* __restrict__ ald,
                                             int M, int K) {
    __shared__ _Float16 sA[64 * LDK];
    __shared__ _Float16 sB[128 * LDK];
    __shared__ float psum_s[4][64];
    __shared__ float psum_d[4][64];
    int tid = threadIdx.x;
    int lane = tid & 63;
    int wv = tid >> 6;
    int m0 = blockIdx.x * 64;
    int quad = lane >> 4;
    int l15 = lane & 15;
    int arow = tid >> 2;
    int ac4 = tid & 3;

    floatx4 acc[4][2] = {};

    for (int k0 = 0; k0 < K; k0 += 32) {
        {
            int gm = m0 + arow;
            int4 va;
            if (gm < M) va = *(const int4*)&A[(size_t)gm * K + k0 + ac4 * 8];
            else        va = make_int4(0, 0, 0, 0);
            *(int4*)&sA[arow * LDK + ac4 * 8] = va;
            #pragma unroll
            for (int r = 0; r < 2; r++) {
                int gn = arow + r * 64;
                int4 vb = *(const int4*)&Bt[(size_t)gn * K + k0 + ac4 * 8];
                *(int4*)&sB[(arow + r * 64) * LDK + ac4 * 8] = vb;
            }
        }
        __syncthreads();
        half8 a[4], b[2];
        #pragma unroll
        for (int i = 0; i < 4; i++)
            a[i] = *(const half8*)&sA[(i * 16 + l15) * LDK + quad * 8];
        #pragma unroll
        for (int j = 0; j < 2; j++)
            b[j] = *(const half8*)&sB[(wv * 32 + j * 16 + l15) * LDK + quad * 8];
        #pragma unroll
        for (int i = 0; i < 4; i++)
            #pragma unroll
            for (int j = 0; j < 2; j++)
                acc[i][j] = __builtin_amdgcn_mfma_f32_16x16x32_f16(a[i], b[j], acc[i][j], 0, 0, 0);
        __syncthreads();
    }
    #pragma unroll
    for (int i = 0; i < 4; i++) {
        #pragma unroll
        for (int r = 0; r < 4; r++) {
            int gm = m0 + i * 16 + quad * 4 + r;
            if (gm < M) {
                #pragma unroll
                for (int j = 0; j < 2; j++)
                    C16[(size_t)gm * OUTD + wv * 32 + j * 16 + l15] = (_Float16)acc[i][j][r];
            }
        }
    }
    float as_v[2], ad_v[2];
    #pragma unroll
    for (int j = 0; j < 2; j++) {
        as_v[j] = a_src[wv * 32 + j * 16 + l15];
        ad_v[j] = a_dst[wv * 32 + j * 16 + l15];
    }
    #pragma unroll
    for (int i = 0; i < 4; i++) {
        #pragma unroll
        for (int r = 0; r < 4; r++) {
            float ps = acc[i][0][r] * as_v[0] + acc[i][1][r] * as_v[1];
            float pd = acc[i][0][r] * ad_v[0] + acc[i][1][r] * ad_v[1];
            #pragma unroll
            for (int off = 1; off <= 8; off <<= 1) {
                ps += __shfl_xor(ps, off);
                pd += __shfl_xor(pd, off);
            }
            if (l15 == 0) {
                int row = i * 16 + quad * 4 + r;
                psum_s[wv][row] = ps;
                psum_d[wv][row] = pd;
            }
        }
    }
    __syncthreads();
    if (tid < 64) {
        int gm = m0 + tid;
        if (gm < M) {
            als[gm] = psum_s[0][tid] + psum_s[1][tid] + psum_s[2][tid] + psum_s[3][tid];
            ald[gm] = psum_d[0][tid] + psum_d[1][tid] + psum_d[2][tid] + psum_d[3][tid];
        }
    }
}

// ---------------- layer-2 edge softmax: max pass + p=exp(t-m) in fp16 + 1/den ----------------
// wave per v; lane = (e_sub 0..7)<<3 | (hd 0..7). pT layout: [ETOT][8] fp16.
// p in (0,1] -- no fp16 overflow. l summed over ROUNDED p so invden normalizes exactly.
__global__ __launch_bounds__(256) void alpha2_kernel(const int* __restrict__ row_ptr,
                                                     const int* __restrict__ csr_src,
                                                     const float* __restrict__ als,
                                                     const float* __restrict__ ald,
                                                     _Float16* __restrict__ pT,
                                                     float* __restrict__ invden) {
    int lane = threadIdx.x & 63;
    int v = blockIdx.x * 4 + (threadIdx.x >> 6);
    if (v >= NN) return;
    int e_sub = lane >> 3;
    int hd = lane & 7;
    float adst = ald[v * NHEADS + hd];
    int s0 = row_ptr[v], s1 = row_ptr[v + 1];
    // pass 1: per-head max (reduce over e_sub = lane bits 3..5)
    float m = -INFINITY;
    for (int base = s0; base < s1; base += 8) {
        int i = base + e_sub;
        if (i < s1) {
            int u = csr_src[i];
            float t = als[u * NHEADS + hd] + adst;
            t = (t > 0.f) ? t : NEG_SLOPE * t;
            m = fmaxf(m, t);
        }
    }
    #pragma unroll
    for (int off = 8; off <= 32; off <<= 1) m = fmaxf(m, __shfl_xor(m, off));
    // pass 2: p = exp(t - m) in (0,1], store fp16, per-head sum of rounded values
    float l = 0.f;
    for (int base = s0; base < s1; base += 8) {
        int i = base + e_sub;
        if (i < s1) {
            int u = csr_src[i];
            float t = als[u * NHEADS + hd] + adst;
            t = (t > 0.f) ? t : NEG_SLOPE * t;
            _Float16 ph = (_Float16)__expf(t - m);
            pT[(size_t)i * 8 + hd] = ph;
            l += (float)ph;
        }
    }
    #pragma unroll
    for (int off = 8; off <= 32; off <<= 1) l += __shfl_xor(l, off);
    if (e_sub == 0) invden[v * NHEADS + hd] = 1.f / (l + 1e-16f);
}

// ---------------- layer-2 gather: channel-chunked, XCD-affine ----------------
// 4 chunks x 128 ch; chunk = (blockIdx&7)>>1 so each chunk's 5MB h-slice maps to
// 2 XCDs' L2 (blockIdx%8 -> XCD dispatch heuristic). Wave per (node, chunk);
// lane owns 2 ch. Chain per edge: csr_src -> h only (p is its own short chain).
__global__ __launch_bounds__(256) void gather2_kernel(const _Float16* __restrict__ h,
                                                      const int* __restrict__ row_ptr,
                                                      const int* __restrict__ csr_src,
                                                      const _Float16* __restrict__ pT,
                                                      const float* __restrict__ invden,
                                                      const float* __restrict__ bias,
                                                      _Float16* __restrict__ gout) {
    int g = blockIdx.x & 7;
    int chunk = g >> 1;
    int ngrp = (blockIdx.x >> 3) * 2 + (g & 1);   // [0, 5000)
    int wv = threadIdx.x >> 6;
    int lane = threadIdx.x & 63;
    int v = ngrp * 4 + wv;                         // [0, 20000)
    int ch = chunk * 128 + lane * 2;
    int hd = ch >> 6;
    int s0 = row_ptr[v], s1 = row_ptr[v + 1];
    float a0 = 0.f, a1 = 0.f;
    int i = s0;
    for (; i + 8 <= s1; i += 8) {
        int u[8]; float p[8]; half2v xv[8];
        #pragma unroll
        for (int e = 0; e < 8; e++) u[e] = csr_src[i + e];
        #pragma unroll
        for (int e = 0; e < 8; e++) p[e] = (float)pT[(size_t)(i + e) * 8 + hd];
        #pragma unroll
        for (int e = 0; e < 8; e++) xv[e] = *(const half2v*)&h[(size_t)u[e] * HCV + ch];
        #pragma unroll
        for (int e = 0; e < 8; e++) {
            a0 = fmaf(p[e], (float)xv[e][0], a0);
            a1 = fmaf(p[e], (float)xv[e][1], a1);
        }
    }
    for (; i < s1; i++) {
        int u0 = csr_src[i];
        float p0 = (float)pT[(size_t)i * 8 + hd];
        half2v x0 = *(const half2v*)&h[(size_t)u0 * HCV + ch];
        a0 = fmaf(p0, (float)x0[0], a0);
        a1 = fmaf(p0, (float)x0[1], a1);
    }
    float inv = invden[v * NHEADS + hd];
    float o0 = fmaf(a0, inv, bias[ch]);
    float o1 = fmaf(a1, inv, bias[ch + 1]);
    o0 = (o0 > 0.f) ? o0 : (__expf(o0) - 1.f);   // ELU
    o1 = (o1 > 0.f) ? o1 : (__expf(o1) - 1.f);
    half2v o; o[0] = (_Float16)o0; o[1] = (_Float16)o1;
    *(half2v*)&gout[(size_t)v * HCV + ch] = o;
}

// ---------------- layer-3 gather (fp16 h3 -> fp32 out, with max pass) ----------------
__global__ __launch_bounds__(256) void gather3_kernel(const _Float16* __restrict__ h,
                                                      const int* __restrict__ row_ptr,
                                                      const int* __restrict__ csr_src,
                                                      const float* __restrict__ als,
                                                      const float* __restrict__ ald,
                                                      const float* __restrict__ bias,
                                                      float* __restrict__ out) {
    int lane = threadIdx.x & 63;
    int v = blockIdx.x * 4 + (threadIdx.x >> 6);
    if (v >= NN) return;
    int e_sub = lane >> 4;
    int cg = lane & 15;
    float adst = ald[v];
    int s0 = row_ptr[v], s1 = row_ptr[v + 1];
    float m = -INFINITY;
    for (int i = s0 + e_sub; i < s1; i += 4) {
        int u = csr_src[i];
        float t = als[u] + adst;
        t = (t > 0.f) ? t : NEG_SLOPE * t;
        m = fmaxf(m, t);
    }
    m = fmaxf(m, __shfl_xor(m, 16));
    m = fmaxf(m, __shfl_xor(m, 32));
    float acc[8] = {};
    float l = 0.f;
    for (int i = s0 + e_sub; i < s1; i += 4) {
        int u = csr_src[i];
        float t = als[u] + adst;
        t = (t > 0.f) ? t : NEG_SLOPE * t;
        float p = __expf(t - m);
        half8 x = *(const half8*)&h[(size_t)u * OUTD + cg * 8];
        l += p;
        #pragma unroll
        for (int j = 0; j < 8; j++)
            acc[j] = fmaf(p, (float)x[j], acc[j]);
    }
    l += __shfl_xor(l, 16);
    l += __shfl_xor(l, 32);
    #pragma unroll
    for (int j = 0; j < 8; j++) {
        acc[j] += __shfl_xor(acc[j], 16);
        acc[j] += __shfl_xor(acc[j], 32);
    }
    if (e_sub == 0) {
        float inv = 1.f / (l + 1e-16f);
        float4 o0, o1;
        o0.x = fmaf(acc[0], inv, bias[cg * 8 + 0]);
        o0.y = fmaf(acc[1], inv, bias[cg * 8 + 1]);
        o0.z = fmaf(acc[2], inv, bias[cg * 8 + 2]);
        o0.w = fmaf(acc[3], inv, bias[cg * 8 + 3]);
        o1.x = fmaf(acc[4], inv, bias[cg * 8 + 4]);
        o1.y = fmaf(acc[5], inv, bias[cg * 8 + 5]);
        o1.z = fmaf(acc[6], inv, bias[cg * 8 + 6]);
        o1.w = fmaf(acc[7], inv, bias[cg * 8 + 7]);
        *(float4*)&out[(size_t)v * OUTD + cg * 8] = o0;
        *(float4*)&out[(size_t)v * OUTD + cg * 8 + 4] = o1;
    }
}

// ---------------- launch ----------------

extern "C" void kernel_launch(void* const* d_in, const int* in_sizes, int n_in,
                              void* d_out, int out_size, void* d_ws, size_t ws_size,
                              hipStream_t stream) {
    const float* x     = (const float*)d_in[0];
    const int*   ei    = (const int*)d_in[1];
    const float* W1    = (const float*)d_in[2];
    const float* as1   = (const float*)d_in[3];
    const float* ad1   = (const float*)d_in[4];
    const float* b1    = (const float*)d_in[5];
    const float* W2    = (const float*)d_in[6];
    const float* as2   = (const float*)d_in[7];
    const float* ad2   = (const float*)d_in[8];
    const float* b2    = (const float*)d_in[9];
    const float* W3    = (const float*)d_in[10];
    const float* as3   = (const float*)d_in[11];
    const float* ad3   = (const float*)d_in[12];
    const float* b3    = (const float*)d_in[13];
    float* out = (float*)d_out;

    size_t off = 0;
    auto carve = [&](size_t bytes) {
        void* p = (char*)d_ws + off;
        off += (bytes + 255) & ~(size_t)255;
        return p;
    };
    int* row_ptr   = (int*)carve((NN + 1) * sizeof(int));
    int* cursor    = (int*)carve(NN * sizeof(int));
    int* csr_src   = (int*)carve(ETOT * sizeof(int));
    _Float16* xh   = (_Float16*)carve((size_t)NN * IND * sizeof(_Float16));
    _Float16* xagg = (_Float16*)carve((size_t)NN * NHEADS * IND * sizeof(_Float16));
    _Float16* gact = (_Float16*)carve((size_t)NN * HCV * sizeof(_Float16));
    _Float16* hf16 = (_Float16*)carve((size_t)NN * HCV * sizeof(_Float16));
    _Float16* h3   = (_Float16*)carve((size_t)NN * OUTD * sizeof(_Float16));
    float* als     = (float*)carve((size_t)NN * NHEADS * sizeof(float));
    float* ald     = (float*)carve((size_t)NN * NHEADS * sizeof(float));
    float* invden  = (float*)carve((size_t)NN * NHEADS * sizeof(float));
    _Float16* pT   = (_Float16*)carve((size_t)ETOT * NHEADS * sizeof(_Float16));
    float* w1p     = (float*)carve((size_t)IND * 16 * sizeof(float));
    _Float16* W1T  = (_Float16*)carve((size_t)S1 * sizeof(_Float16));
    _Float16* W2T  = (_Float16*)carve((size_t)S2 * sizeof(_Float16));
    _Float16* W3T  = (_Float16*)carve((size_t)S3 * sizeof(_Float16));
    _Float16* gact2 = xagg;   // aliases xagg (dead after gemm1_bd)
    (void)ws_size; (void)n_in; (void)in_sizes; (void)out_size;

    dim3 blk(256);

    // ---- prep ----
    int prep_n = STOT + NN + XTOT + IND * 16;
    prep_kernel<<<(prep_n + 255) / 256, blk, 0, stream>>>(W1, W2, W3, x, as1, ad1,
        W1T, W2T, W3T, xh, w1p, cursor);

    // ---- CSR build ----
    count_kernel<<<(ETOT + 255) / 256, blk, 0, stream>>>(ei, cursor);
    scan_kernel<<<1, 1024, 0, stream>>>(cursor, row_ptr, cursor);
    fill_kernel<<<(ETOT + 255) / 256, blk, 0, stream>>>(ei, cursor, csr_src);

    int mt64 = (NN + 63) / 64;
    int nwaves_n = (NN + 3) / 4;

    // ---- layer 1: input-side aggregation (wave per node) ----
    al1_thin<<<(NN * 16 + 255) / 256, blk, 0, stream>>>(x, w1p, als, ald);
    gather1_kernel<<<nwaves_n, blk, 0, stream>>>(xh, row_ptr, csr_src, als, ald, xagg);
    gemm1_bd<<<dim3(mt64, NHEADS), blk, 0, stream>>>(xagg, W1T, b1, gact, NN);

    // ---- layer 2: output-side; split alpha (with max) + chunked XCD-affine gather ----
    gemm_l2<<<dim3(mt64, HCV / 128), blk, 0, stream>>>(gact, W2T, hf16, as2, ad2, als, ald, NN, HCV);
    alpha2_kernel<<<nwaves_n, blk, 0, stream>>>(row_ptr, csr_src, als, ald, pT, invden);
    gather2_kernel<<<NN, blk, 0, stream>>>(hf16, row_ptr, csr_src, pT, invden, b2, gact2);

    // ---- layer 3: output-side, fp16 h3 ----
    gemm3<<<dim3(mt64, 1), blk, 0, stream>>>(gact2, W3T, h3, as3, ad3, als, ald, NN, HCV);
    gather3_kernel<<<nwaves_n, blk, 0, stream>>>(h3, row_ptr, csr_src, als, ald, b3, out);
}

// Round 17
// 340.167 us; speedup vs baseline: 1.0593x; 1.0593x over previous
//
#include <hip/hip_runtime.h>
#include <math.h>

#define NN 20000
#define EE 320000
#define ETOT 340000   // EE + NN self-loops
#define NHEADS 8
#define HID 64
#define HCV 512       // NHEADS*HID
#define IND 128
#define OUTD 128
#define NEG_SLOPE 0.2f

typedef __attribute__((ext_vector_type(8))) _Float16 half8;
typedef __attribute__((ext_vector_type(4))) float floatx4;

// ---------------- prep: W cvt + x cvt + w1 projection + zero cnt ----------------
__device__ __forceinline__ void cvt_one(const float* W, _Float16* T, int idx, int K, int N) {
    int k = idx / N, n = idx - k * N;
    T[(size_t)n * K + k] = (_Float16)W[idx];
}

#define S1 (IND * HCV)
#define S2 (HCV * HCV)
#define S3 (HCV * OUTD)
#define STOT (S1 + S2 + S3)
#define XTOT (NN * IND)
__global__ void prep_kernel(const float* __restrict__ W1, const float* __restrict__ W2,
                            const float* __restrict__ W3, const float* __restrict__ x,
                            const float* __restrict__ as1, const float* __restrict__ ad1,
                            _Float16* __restrict__ T1, _Float16* __restrict__ T2,
                            _Float16* __restrict__ T3, _Float16* __restrict__ xh,
                            float* __restrict__ w1p, int* __restrict__ cnt) {
    int idx = blockIdx.x * blockDim.x + threadIdx.x;
    if (idx < S1) cvt_one(W1, T1, idx, IND, HCV);
    else if (idx < S1 + S2) cvt_one(W2, T2, idx - S1, HCV, HCV);
    else if (idx < STOT) cvt_one(W3, T3, idx - S1 - S2, HCV, OUTD);
    else if (idx < STOT + NN) cnt[idx - STOT] = 0;
    else if (idx < STOT + NN + XTOT) {
        int j = idx - STOT - NN;
        xh[j] = (_Float16)x[j];
    } else if (idx < STOT + NN + XTOT + IND * 16) {
        int j = idx - STOT - NN - XTOT;
        int c = j >> 4, o = j & 15;
        int hh = o & 7;
        const float* av = (o < 8) ? as1 : ad1;
        float s = 0.f;
        #pragma unroll 8
        for (int jj = 0; jj < HID; jj++)
            s = fmaf(W1[c * HCV + hh * HID + jj], av[hh * HID + jj], s);
        w1p[c * 16 + o] = s;
    }
}

// ---------------- CSR build ----------------

__global__ void count_kernel(const int* __restrict__ ei, int* __restrict__ cnt) {
    int i = blockIdx.x * blockDim.x + threadIdx.x;
    if (i >= ETOT) return;
    int v = (i < EE) ? ei[EE + i] : (i - EE);
    atomicAdd(&cnt[v], 1);
}

#define SCH 20
__global__ __launch_bounds__(1024) void scan_kernel(const int* __restrict__ cnt,
                                                    int* __restrict__ row_ptr,
                                                    int* __restrict__ cursor) {
    __shared__ int wtot[16];
    __shared__ int woff[16];
    int t = threadIdx.x;
    int lane = t & 63;
    int wid = t >> 6;
    int base = t * SCH;
    int vals[SCH];
    int s = 0;
    #pragma unroll
    for (int i = 0; i < SCH; i++) {
        int idx = base + i;
        int v = (idx < NN) ? cnt[idx] : 0;
        vals[i] = v;
        s += v;
    }
    int incl = s;
    #pragma unroll
    for (int off = 1; off < 64; off <<= 1) {
        int u = __shfl_up(incl, off);
        if (lane >= off) incl += u;
    }
    int excl = incl - s;
    if (lane == 63) wtot[wid] = incl;
    __syncthreads();
    if (t == 0) {
        int run = 0;
        #pragma unroll
        for (int j = 0; j < 16; j++) { woff[j] = run; run += wtot[j]; }
        row_ptr[NN] = run;
    }
    __syncthreads();
    int run = woff[wid] + excl;
    #pragma unroll
    for (int i = 0; i < SCH; i++) {
        int idx = base + i;
        if (idx < NN) { row_ptr[idx] = run; cursor[idx] = run; run += vals[i]; }
    }
}

__global__ void fill_kernel(const int* __restrict__ ei, int* __restrict__ cursor,
                            int* __restrict__ csr_src) {
    int i = blockIdx.x * blockDim.x + threadIdx.x;
    if (i >= ETOT) return;
    int u, v;
    if (i < EE) { u = ei[i]; v = ei[EE + i]; }
    else        { u = i - EE; v = i - EE; }
    int pos = atomicAdd(&cursor[v], 1);
    csr_src[pos] = u;
}

// ---------------- layer-1 half-logits from x (thin dot) ----------------
__global__ void al1_thin(const float* __restrict__ x, const float* __restrict__ w1p,
                         float* __restrict__ als, float* __restrict__ ald) {
    int gid = blockIdx.x * blockDim.x + threadIdx.x;
    int node = gid >> 4, o = gid & 15;
    if (node >= NN) return;
    const float* xr = x + (size_t)node * IND;
    float s = 0.f;
    #pragma unroll 4
    for (int c = 0; c < IND; c++)
        s = fmaf(xr[c], w1p[c * 16 + o], s);
    if (o < 8) als[node * 8 + o] = s;
    else       ald[node * 8 + (o - 8)] = s;
}

// ---------------- layer-1 gather: wave per node, per-head agg of x, unroll 4 ----------------
__global__ __launch_bounds__(256) void gather1_kernel(const _Float16* __restrict__ xh,
                                                      const int* __restrict__ row_ptr,
                                                      const int* __restrict__ csr_src,
                                                      const float* __restrict__ als,
                                                      const float* __restrict__ ald,
                                                      _Float16* __restrict__ xagg) {
    int lane = threadIdx.x & 63;
    int v = blockIdx.x * 4 + (threadIdx.x >> 6);
    if (v >= NN) return;
    int hd = lane >> 3;
    int cg = lane & 7;
    float adst = ald[v * NHEADS + hd];
    int s0 = row_ptr[v], s1 = row_ptr[v + 1];
    float acc[16] = {};
    float l = 0.f;
    int i = s0;
    for (; i + 4 <= s1; i += 4) {
        int u[4]; float p[4];
        #pragma unroll
        for (int e = 0; e < 4; e++) u[e] = csr_src[i + e];
        #pragma unroll
        for (int e = 0; e < 4; e++) {
            float t = als[u[e] * NHEADS + hd] + adst;
            t = (t > 0.f) ? t : NEG_SLOPE * t;
            p[e] = __expf(fminf(t, 80.f));
        }
        half8 a[4], b[4];
        #pragma unroll
        for (int e = 0; e < 4; e++) {
            a[e] = *(const half8*)&xh[(size_t)u[e] * IND + cg * 16];
            b[e] = *(const half8*)&xh[(size_t)u[e] * IND + cg * 16 + 8];
        }
        #pragma unroll
        for (int e = 0; e < 4; e++) {
            l += p[e];
            #pragma unroll
            for (int j = 0; j < 8; j++) {
                acc[j]     = fmaf(p[e], (float)a[e][j], acc[j]);
                acc[j + 8] = fmaf(p[e], (float)b[e][j], acc[j + 8]);
            }
        }
    }
    for (; i < s1; i++) {
        int u0 = csr_src[i];
        float t0 = als[u0 * NHEADS + hd] + adst;
        t0 = (t0 > 0.f) ? t0 : NEG_SLOPE * t0;
        float p0 = __expf(fminf(t0, 80.f));
        half8 a0 = *(const half8*)&xh[(size_t)u0 * IND + cg * 16];
        half8 b0 = *(const half8*)&xh[(size_t)u0 * IND + cg * 16 + 8];
        l += p0;
        #pragma unroll
        for (int j = 0; j < 8; j++) {
            acc[j]     = fmaf(p0, (float)a0[j], acc[j]);
            acc[j + 8] = fmaf(p0, (float)b0[j], acc[j + 8]);
        }
    }
    float inv = 1.f / (l + 1e-16f);
    half8 o0, o1;
    #pragma unroll
    for (int j = 0; j < 8; j++) {
        o0[j] = (_Float16)(acc[j] * inv);
        o1[j] = (_Float16)(acc[j + 8] * inv);
    }
    size_t base = (size_t)v * (NHEADS * IND) + hd * IND + cg * 16;
    *(half8*)&xagg[base] = o0;
    *(half8*)&xagg[base + 8] = o1;
}

// ---------------- block-diagonal GEMM (layer 1) ----------------
#define LDK 40
__global__ __launch_bounds__(256) void gemm1_bd(const _Float16* __restrict__ xagg,
                                                const _Float16* __restrict__ Bt,
                                                const float* __restrict__ bias,
                                                _Float16* __restrict__ gact,
                                                int M) {
    __shared__ _Float16 sA[64 * LDK];
    __shared__ _Float16 sB[64 * LDK];
    int tid = threadIdx.x;
    int lane = tid & 63;
    int wv = tid >> 6;
    int m0 = blockIdx.x * 64;
    int h = blockIdx.y;
    int quad = lane >> 4;
    int l15 = lane & 15;
    int arow = tid >> 2;
    int ac4 = tid & 3;

    floatx4 acc[4] = {};

    for (int k0 = 0; k0 < IND; k0 += 32) {
        {
            int gm = m0 + arow;
            int4 va;
            if (gm < M) va = *(const int4*)&xagg[(size_t)gm * (NHEADS * IND) + h * IND + k0 + ac4 * 8];
            else        va = make_int4(0, 0, 0, 0);
            *(int4*)&sA[arow * LDK + ac4 * 8] = va;
            int gn = h * 64 + arow;
            int4 vb = *(const int4*)&Bt[(size_t)gn * IND + k0 + ac4 * 8];
            *(int4*)&sB[arow * LDK + ac4 * 8] = vb;
        }
        __syncthreads();
        half8 a[4], b;
        #pragma unroll
        for (int i = 0; i < 4; i++)
            a[i] = *(const half8*)&sA[(i * 16 + l15) * LDK + quad * 8];
        b = *(const half8*)&sB[(wv * 16 + l15) * LDK + quad * 8];
        #pragma unroll
        for (int i = 0; i < 4; i++)
            acc[i] = __builtin_amdgcn_mfma_f32_16x16x32_f16(a[i], b, acc[i], 0, 0, 0);
        __syncthreads();
    }
    #pragma unroll
    for (int i = 0; i < 4; i++) {
        #pragma unroll
        for (int r = 0; r < 4; r++) {
            int gm = m0 + i * 16 + quad * 4 + r;
            if (gm < M) {
                int col = h * 64 + wv * 16 + l15;
                float o = acc[i][r] + bias[col];
                o = (o > 0.f) ? o : (__expf(o) - 1.f);
                gact[(size_t)gm * HCV + col] = (_Float16)o;
            }
        }
    }
}

// ---------------- MFMA GEMM 64x128 (layer 2): f16, fused al epilogue ----------------
__global__ __launch_bounds__(256) void gemm_l2(const _Float16* __restrict__ A,
                                               const _Float16* __restrict__ Bt,
                                               _Float16* __restrict__ C16,
                                               const float* __restrict__ a_src,
                                               const float* __restrict__ a_dst,
                                               float* __restrict__ als,
                                               float* __restrict__ ald,
                                               int M, int K) {
    __shared__ _Float16 sA[64 * LDK];
    __shared__ _Float16 sB[128 * LDK];
    __shared__ float psum_s[4][64];
    __shared__ float psum_d[4][64];
    int tid = threadIdx.x;
    int lane = tid & 63;
    int wv = tid >> 6;
    int m0 = blockIdx.x * 64, n0 = blockIdx.y * 128;
    int quad = lane >> 4;
    int l15 = lane & 15;
    int arow = tid >> 2;
    int ac4 = tid & 3;

    floatx4 acc[4][2] = {};

    for (int k0 = 0; k0 < K; k0 += 32) {
        {
            int gm = m0 + arow;
            int4 va;
            if (gm < M) va = *(const int4*)&A[(size_t)gm * K + k0 + ac4 * 8];
            else        va = make_int4(0, 0, 0, 0);
            *(int4*)&sA[arow * LDK + ac4 * 8] = va;
            #pragma unroll
            for (int r = 0; r < 2; r++) {
                int gn = n0 + arow + r * 64;
                int4 vb = *(const int4*)&Bt[(size_t)gn * K + k0 + ac4 * 8];
                *(int4*)&sB[(arow + r * 64) * LDK + ac4 * 8] = vb;
            }
        }
        __syncthreads();
        half8 a[4], b[2];
        #pragma unroll
        for (int i = 0; i < 4; i++)
            a[i] = *(const half8*)&sA[(i * 16 + l15) * LDK + quad * 8];
        #pragma unroll
        for (int j = 0; j < 2; j++)
            b[j] = *(const half8*)&sB[(wv * 32 + j * 16 + l15) * LDK + quad * 8];
        #pragma unroll
        for (int i = 0; i < 4; i++)
            #pragma unroll
            for (int j = 0; j < 2; j++)
                acc[i][j] = __builtin_amdgcn_mfma_f32_16x16x32_f16(a[i], b[j], acc[i][j], 0, 0, 0);
        __syncthreads();
    }
    #pragma unroll
    for (int i = 0; i < 4; i++) {
        #pragma unroll
        for (int r = 0; r < 4; r++) {
            int gm = m0 + i * 16 + quad * 4 + r;
            if (gm < M) {
                #pragma unroll
                for (int j = 0; j < 2; j++)
                    C16[(size_t)gm * HCV + n0 + wv * 32 + j * 16 + l15] = (_Float16)acc[i][j][r];
            }
        }
    }
    int h0 = n0 >> 6;
    float as_v[2], ad_v[2];
    #pragma unroll
    for (int j = 0; j < 2; j++) {
        int dim = (wv * 32 + j * 16 + l15) & 63;
        int hh = h0 + (wv >> 1);
        as_v[j] = a_src[hh * HID + dim];
        ad_v[j] = a_dst[hh * HID + dim];
    }
    #pragma unroll
    for (int i = 0; i < 4; i++) {
        #pragma unroll
        for (int r = 0; r < 4; r++) {
            float ps = acc[i][0][r] * as_v[0] + acc[i][1][r] * as_v[1];
            float pd = acc[i][0][r] * ad_v[0] + acc[i][1][r] * ad_v[1];
            #pragma unroll
            for (int off = 1; off <= 8; off <<= 1) {
                ps += __shfl_xor(ps, off);
                pd += __shfl_xor(pd, off);
            }
            if (l15 == 0) {
                int row = i * 16 + quad * 4 + r;
                psum_s[wv][row] = ps;
                psum_d[wv][row] = pd;
            }
        }
    }
    __syncthreads();
    if (tid < 64) {
        int gm = m0 + tid;
        if (gm < M) {
            als[gm * NHEADS + h0]     = psum_s[0][tid] + psum_s[1][tid];
            als[gm * NHEADS + h0 + 1] = psum_s[2][tid] + psum_s[3][tid];
            ald[gm * NHEADS + h0]     = psum_d[0][tid] + psum_d[1][tid];
            ald[gm * NHEADS + h0 + 1] = psum_d[2][tid] + psum_d[3][tid];
        }
    }
}

// ---------------- MFMA GEMM 64x128 (layer 3): f16 C out, fused al3 ----------------
__global__ __launch_bounds__(256) void gemm3(const _Float16* __restrict__ A,
                                             const _Float16* __restrict__ Bt,
                                             _Float16* __restrict__ C16,
                                             const float* __restrict__ a_src,
                                             const float* __restrict__ a_dst,
                                             float* __restrict__ als,
                                             float* __restrict__ ald,
                                             int M, int K) {
    __shared__ _Float16 sA[64 * LDK];
    __shared__ _Float16 sB[128 * LDK];
    __shared__ float psum_s[4][64];
    __shared__ float psum_d[4][64];
    int tid = threadIdx.x;
    int lane = tid & 63;
    int wv = tid >> 6;
    int m0 = blockIdx.x * 64;
    int quad = lane >> 4;
    int l15 = lane & 15;
    int arow = tid >> 2;
    int ac4 = tid & 3;

    floatx4 acc[4][2] = {};

    for (int k0 = 0; k0 < K; k0 += 32) {
        {
            int gm = m0 + arow;
            int4 va;
            if (gm < M) va = *(const int4*)&A[(size_t)gm * K + k0 + ac4 * 8];
            else        va = make_int4(0, 0, 0, 0);
            *(int4*)&sA[arow * LDK + ac4 * 8] = va;
            #pragma unroll
            for (int r = 0; r < 2; r++) {
                int gn = arow + r * 64;
                int4 vb = *(const int4*)&Bt[(size_t)gn * K + k0 + ac4 * 8];
                *(int4*)&sB[(arow + r * 64) * LDK + ac4 * 8] = vb;
            }
        }
        __syncthreads();
        half8 a[4], b[2];
        #pragma unroll
        for (int i = 0; i < 4; i++)
            a[i] = *(const half8*)&sA[(i * 16 + l15) * LDK + quad * 8];
        #pragma unroll
        for (int j = 0; j < 2; j++)
            b[j] = *(const half8*)&sB[(wv * 32 + j * 16 + l15) * LDK + quad * 8];
        #pragma unroll
        for (int i = 0; i < 4; i++)
            #pragma unroll
            for (int j = 0; j < 2; j++)
                acc[i][j] = __builtin_amdgcn_mfma_f32_16x16x32_f16(a[i], b[j], acc[i][j], 0, 0, 0);
        __syncthreads();
    }
    #pragma unroll
    for (int i = 0; i < 4; i++) {
        #pragma unroll
        for (int r = 0; r < 4; r++) {
            int gm = m0 + i * 16 + quad * 4 + r;
            if (gm < M) {
                #pragma unroll
                for (int j = 0; j < 2; j++)
                    C16[(size_t)gm * OUTD + wv * 32 + j * 16 + l15] = (_Float16)acc[i][j][r];
            }
        }
    }
    float as_v[2], ad_v[2];
    #pragma unroll
    for (int j = 0; j < 2; j++) {
        as_v[j] = a_src[wv * 32 + j * 16 + l15];
        ad_v[j] = a_dst[wv * 32 + j * 16 + l15];
    }
    #pragma unroll
    for (int i = 0; i < 4; i++) {
        #pragma unroll
        for (int r = 0; r < 4; r++) {
            float ps = acc[i][0][r] * as_v[0] + acc[i][1][r] * as_v[1];
            float pd = acc[i][0][r] * ad_v[0] + acc[i][1][r] * ad_v[1];
            #pragma unroll
            for (int off = 1; off <= 8; off <<= 1) {
                ps += __shfl_xor(ps, off);
                pd += __shfl_xor(pd, off);
            }
            if (l15 == 0) {
                int row = i * 16 + quad * 4 + r;
                psum_s[wv][row] = ps;
                psum_d[wv][row] = pd;
            }
        }
    }
    __syncthreads();
    if (tid < 64) {
        int gm = m0 + tid;
        if (gm < M) {
            als[gm] = psum_s[0][tid] + psum_s[1][tid] + psum_s[2][tid] + psum_s[3][tid];
            ald[gm] = psum_d[0][tid] + psum_d[1][tid] + psum_d[2][tid] + psum_d[3][tid];
        }
    }
}

// ---------------- layer-2 gather: wave per node, unroll 8 ----------------
__global__ __launch_bounds__(256) void gather2_kernel(const _Float16* __restrict__ h,
                                                      const int* __restrict__ row_ptr,
                                                      const int* __restrict__ csr_src,
                                                      const float* __restrict__ als,
                                                      const float* __restrict__ ald,
                                                      const float* __restrict__ bias,
                                                      _Float16* __restrict__ gout) {
    int lane = threadIdx.x & 63;
    int v = blockIdx.x * 4 + (threadIdx.x >> 6);
    if (v >= NN) return;
    int hd = lane >> 3;
    float adst = ald[v * NHEADS + hd];
    int s0 = row_ptr[v], s1 = row_ptr[v + 1];
    float acc[8] = {};
    float l = 0.f;
    int i = s0;
    for (; i + 8 <= s1; i += 8) {
        int u[8]; float p[8];
        #pragma unroll
        for (int e = 0; e < 8; e++) u[e] = csr_src[i + e];
        #pragma unroll
        for (int e = 0; e < 8; e++) {
            float t = als[u[e] * NHEADS + hd] + adst;
            t = (t > 0.f) ? t : NEG_SLOPE * t;
            p[e] = __expf(fminf(t, 80.f));
        }
        half8 xv[8];
        #pragma unroll
        for (int e = 0; e < 8; e++)
            xv[e] = *(const half8*)&h[(size_t)u[e] * HCV + lane * 8];
        #pragma unroll
        for (int e = 0; e < 8; e++) {
            l += p[e];
            #pragma unroll
            for (int j = 0; j < 8; j++)
                acc[j] = fmaf(p[e], (float)xv[e][j], acc[j]);
        }
    }
    for (; i + 2 <= s1; i += 2) {
        int u0 = csr_src[i], u1 = csr_src[i + 1];
        float t0 = als[u0 * NHEADS + hd] + adst;
        float t1 = als[u1 * NHEADS + hd] + adst;
        t0 = (t0 > 0.f) ? t0 : NEG_SLOPE * t0;
        t1 = (t1 > 0.f) ? t1 : NEG_SLOPE * t1;
        float p0 = __expf(fminf(t0, 80.f));
        float p1 = __expf(fminf(t1, 80.f));
        half8 x0 = *(const half8*)&h[(size_t)u0 * HCV + lane * 8];
        half8 x1 = *(const half8*)&h[(size_t)u1 * HCV + lane * 8];
        l += p0 + p1;
        #pragma unroll
        for (int j = 0; j < 8; j++) {
            acc[j] = fmaf(p0, (float)x0[j], acc[j]);
            acc[j] = fmaf(p1, (float)x1[j], acc[j]);
        }
    }
    if (i < s1) {
        int u0 = csr_src[i];
        float t0 = als[u0 * NHEADS + hd] + adst;
        t0 = (t0 > 0.f) ? t0 : NEG_SLOPE * t0;
        float p0 = __expf(fminf(t0, 80.f));
        half8 x0 = *(const half8*)&h[(size_t)u0 * HCV + lane * 8];
        l += p0;
        #pragma unroll
        for (int j = 0; j < 8; j++)
            acc[j] = fmaf(p0, (float)x0[j], acc[j]);
    }
    float inv = 1.f / (l + 1e-16f);
    half8 hv;
    #pragma unroll
    for (int j = 0; j < 8; j++) {
        float o = fmaf(acc[j], inv, bias[lane * 8 + j]);
        o = (o > 0.f) ? o : (__expf(o) - 1.f);   // ELU
        hv[j] = (_Float16)o;
    }
    *(half8*)&gout[(size_t)v * HCV + lane * 8] = hv;
}

// ---------------- layer-3 gather (fp16 h3 -> fp32 out, with max pass) ----------------
__global__ __launch_bounds__(256) void gather3_kernel(const _Float16* __restrict__ h,
                                                      const int* __restrict__ row_ptr,
                                                      const int* __restrict__ csr_src,
                                                      const float* __restrict__ als,
                                                      const float* __restrict__ ald,
                                                      const float* __restrict__ bias,
                                                      float* __restrict__ out) {
    int lane = threadIdx.x & 63;
    int v = blockIdx.x * 4 + (threadIdx.x >> 6);
    if (v >= NN) return;
    int e_sub = lane >> 4;
    int cg = lane & 15;
    float adst = ald[v];
    int s0 = row_ptr[v], s1 = row_ptr[v + 1];
    float m = -INFINITY;
    for (int i = s0 + e_sub; i < s1; i += 4) {
        int u = csr_src[i];
        float t = als[u] + adst;
        t = (t > 0.f) ? t : NEG_SLOPE * t;
        m = fmaxf(m, t);
    }
    m = fmaxf(m, __shfl_xor(m, 16));
    m = fmaxf(m, __shfl_xor(m, 32));
    float acc[8] = {};
    float l = 0.f;
    for (int i = s0 + e_sub; i < s1; i += 4) {
        int u = csr_src[i];
        float t = als[u] + adst;
        t = (t > 0.f) ? t : NEG_SLOPE * t;
        float p = __expf(t - m);
        half8 x = *(const half8*)&h[(size_t)u * OUTD + cg * 8];
        l += p;
        #pragma unroll
        for (int j = 0; j < 8; j++)
            acc[j] = fmaf(p, (float)x[j], acc[j]);
    }
    l += __shfl_xor(l, 16);
    l += __shfl_xor(l, 32);
    #pragma unroll
    for (int j = 0; j < 8; j++) {
        acc[j] += __shfl_xor(acc[j], 16);
        acc[j] += __shfl_xor(acc[j], 32);
    }
    if (e_sub == 0) {
        float inv = 1.f / (l + 1e-16f);
        float4 o0, o1;
        o0.x = fmaf(acc[0], inv, bias[cg * 8 + 0]);
        o0.y = fmaf(acc[1], inv, bias[cg * 8 + 1]);
        o0.z = fmaf(acc[2], inv, bias[cg * 8 + 2]);
        o0.w = fmaf(acc[3], inv, bias[cg * 8 + 3]);
        o1.x = fmaf(acc[4], inv, bias[cg * 8 + 4]);
        o1.y = fmaf(acc[5], inv, bias[cg * 8 + 5]);
        o1.z = fmaf(acc[6], inv, bias[cg * 8 + 6]);
        o1.w = fmaf(acc[7], inv, bias[cg * 8 + 7]);
        *(float4*)&out[(size_t)v * OUTD + cg * 8] = o0;
        *(float4*)&out[(size_t)v * OUTD + cg * 8 + 4] = o1;
    }
}

// ---------------- launch ----------------

extern "C" void kernel_launch(void* const* d_in, const int* in_sizes, int n_in,
                              void* d_out, int out_size, void* d_ws, size_t ws_size,
                              hipStream_t stream) {
    const float* x     = (const float*)d_in[0];
    const int*   ei    = (const int*)d_in[1];
    const float* W1    = (const float*)d_in[2];
    const float* as1   = (const float*)d_in[3];
    const float* ad1   = (const float*)d_in[4];
    const float* b1    = (const float*)d_in[5];
    const float* W2    = (const float*)d_in[6];
    const float* as2   = (const float*)d_in[7];
    const float* ad2   = (const float*)d_in[8];
    const float* b2    = (const float*)d_in[9];
    const float* W3    = (const float*)d_in[10];
    const float* as3   = (const float*)d_in[11];
    const float* ad3   = (const float*)d_in[12];
    const float* b3    = (const float*)d_in[13];
    float* out = (float*)d_out;

    size_t off = 0;
    auto carve = [&](size_t bytes) {
        void* p = (char*)d_ws + off;
        off += (bytes + 255) & ~(size_t)255;
        return p;
    };
    int* row_ptr   = (int*)carve((NN + 1) * sizeof(int));
    int* cursor    = (int*)carve(NN * sizeof(int));
    int* csr_src   = (int*)carve(ETOT * sizeof(int));
    _Float16* xh   = (_Float16*)carve((size_t)NN * IND * sizeof(_Float16));
    _Float16* xagg = (_Float16*)carve((size_t)NN * NHEADS * IND * sizeof(_Float16));
    _Float16* gact = (_Float16*)carve((size_t)NN * HCV * sizeof(_Float16));
    _Float16* hf16 = (_Float16*)carve((size_t)NN * HCV * sizeof(_Float16));
    _Float16* h3   = (_Float16*)carve((size_t)NN * OUTD * sizeof(_Float16));
    float* als     = (float*)carve((size_t)NN * NHEADS * sizeof(float));
    float* ald     = (float*)carve((size_t)NN * NHEADS * sizeof(float));
    float* w1p     = (float*)carve((size_t)IND * 16 * sizeof(float));
    _Float16* W1T  = (_Float16*)carve((size_t)S1 * sizeof(_Float16));
    _Float16* W2T  = (_Float16*)carve((size_t)S2 * sizeof(_Float16));
    _Float16* W3T  = (_Float16*)carve((size_t)S3 * sizeof(_Float16));
    _Float16* gact2 = xagg;   // aliases xagg (dead after gemm1_bd)
    (void)ws_size; (void)n_in; (void)in_sizes; (void)out_size;

    dim3 blk(256);

    // ---- prep ----
    int prep_n = STOT + NN + XTOT + IND * 16;
    prep_kernel<<<(prep_n + 255) / 256, blk, 0, stream>>>(W1, W2, W3, x, as1, ad1,
        W1T, W2T, W3T, xh, w1p, cursor);

    // ---- CSR build ----
    count_kernel<<<(ETOT + 255) / 256, blk, 0, stream>>>(ei, cursor);
    scan_kernel<<<1, 1024, 0, stream>>>(cursor, row_ptr, cursor);
    fill_kernel<<<(ETOT + 255) / 256, blk, 0, stream>>>(ei, cursor, csr_src);

    int mt64 = (NN + 63) / 64;
    int nwaves_n = (NN + 3) / 4;

    // ---- layer 1: input-side aggregation (wave per node) ----
    al1_thin<<<(NN * 16 + 255) / 256, blk, 0, stream>>>(x, w1p, als, ald);
    gather1_kernel<<<nwaves_n, blk, 0, stream>>>(xh, row_ptr, csr_src, als, ald, xagg);
    gemm1_bd<<<dim3(mt64, NHEADS), blk, 0, stream>>>(xagg, W1T, b1, gact, NN);

    // ---- layer 2: output-side (wave per node gather, unroll 8) ----
    gemm_l2<<<dim3(mt64, HCV / 128), blk, 0, stream>>>(gact, W2T, hf16, as2, ad2, als, ald, NN, HCV);
    gather2_kernel<<<nwaves_n, blk, 0, stream>>>(hf16, row_ptr, csr_src, als, ald, b2, gact2);

    // ---- layer 3: output-side, fp16 h3 ----
    gemm3<<<dim3(mt64, 1), blk, 0, stream>>>(gact2, W3T, h3, as3, ad3, als, ald, NN, HCV);
    gather3_kernel<<<nwaves_n, blk, 0, stream>>>(h3, row_ptr, csr_src, als, ald, b3, out);
}